// Round 8
// baseline (198.888 us; speedup 1.0000x reference)
//
#include <hip/hip_runtime.h>
#include <stdint.h>

typedef int   v4i  __attribute__((ext_vector_type(4)));
typedef int   v16i __attribute__((ext_vector_type(16)));
typedef float v4f  __attribute__((ext_vector_type(4)));

// xt layout: [n][hp=58][wp=66][ci=128] int8, zero-padded (hp-1,wp-1 are src coords)
#define XT_H_STRIDE (66*128)          // 8448
#define XT_N_STRIDE (58*66*128)       // 489984
#define XT_BYTES    (32*58*66*128)    // 15,679,488
#define WQ_BYTES    (256*1152)        // 294,912

__device__ __forceinline__ void gload16(const void* g, void* l) {
  __builtin_amdgcn_global_load_lds(
      (const __attribute__((address_space(1))) void*)g,
      (__attribute__((address_space(3))) void*)l, 16, 0, 0);
}

// ---------------- x transform: fp32 NCHW -> int8 [n][hp][wp][ci] ----------------
// Coalesced both sides via LDS transpose. Unchanged (proven).
__global__ __launch_bounds__(256) void xform_x(const float* __restrict__ x,
                                               char* __restrict__ xt) {
  __shared__ int LB[56 * 33];          // [w][32 ci-dwords + 1 pad]
  int bid = blockIdx.x;                // 32*58
  int n  = bid / 58;
  int hp = bid - n * 58;
  int t  = threadIdx.x;
  int srch = hp - 1;
  bool rowok = (srch >= 0) && (srch < 56);
  char* dstrow = xt + (size_t)n * XT_N_STRIDE + (size_t)hp * XT_H_STRIDE;

  if (rowok) {
    const float* rb = x + ((size_t)(n * 128) * 56 + srch) * 56;   // + ci*3136 + w
#pragma unroll
    for (int u0 = 0; u0 < 2; ++u0) {
      int u  = t + u0 * 256;
      int wb = u & 15;
      int cb = u >> 4;
      int w0 = wb * 4, ci0 = cb * 4;
      if (w0 < 56) {
        int dw[4] = {0, 0, 0, 0};
#pragma unroll
        for (int i = 0; i < 4; ++i) {
          v4f f = *(const v4f*)(rb + (size_t)(ci0 + i) * 3136 + w0);
#pragma unroll
          for (int j = 0; j < 4; ++j)
            dw[j] |= (((int)f[j]) & 255) << (8 * i);
        }
#pragma unroll
        for (int j = 0; j < 4; ++j)
          LB[(w0 + j) * 33 + cb] = dw[j];
      }
    }
    __syncthreads();
    for (int c = t; c < 528; c += 256) {
      int wp  = c >> 3;
      int cio = c & 7;
      int srw = wp - 1;
      v4i v = {0, 0, 0, 0};
      if (srw >= 0 && srw < 56) {
#pragma unroll
        for (int k = 0; k < 4; ++k) v[k] = LB[srw * 33 + cio * 4 + k];
      }
      *(v4i*)(dstrow + c * 16) = v;
    }
  } else {
    v4i z = {0, 0, 0, 0};
    for (int c = t; c < 528; c += 256) *(v4i*)(dstrow + c * 16) = z;
  }
}

// ---------------- w transform: OIHW fp32 -> int8 wq3 + scale ----------------
// Layout: [kt18][mhalf2][chunk4][co128][16] int8 (R9, unchanged). Per kt the
// 16KB panel is contiguous in exactly DMA-linear order, and A-frag ds_reads
// (chunk = kk*2+hi, row = fi*32+l31) are lane-contiguous 512B runs.
__global__ __launch_bounds__(256) void xform_w(const float* __restrict__ wsrc,
                                               const int* __restrict__ Aq,
                                               const int* __restrict__ Nq,
                                               char* __restrict__ wq3,
                                               float* __restrict__ scale) {
  int idx = blockIdx.x * 256 + threadIdx.x;    // 294912
  int co = idx / 1152;
  int k  = idx - co * 1152;          // K index: g*128 + ci
  int g  = k >> 7;
  int ci = k & 127;
  int kh = g / 3;
  int kw = g - 3 * kh;
  float f = wsrc[(size_t)(co * 128 + ci) * 9 + kh * 3 + kw];
  int kt    = k >> 6;                // 0..17 (BK=64 window)
  int mhalf = co >> 7;
  int chunk = (k >> 4) & 3;          // 16B k-chunk within BK=64
  int row   = co & 127;
  int col   = k & 15;
  wq3[(((kt * 2 + mhalf) * 4 + chunk) * 128 + row) * 16 + col] = (signed char)(int)f;
  if (idx < 256) {
    scale[idx] = (float)Aq[idx] * exp2f(-(float)Nq[idx]);   // exact: A < 2^15
  }
}

// ---------------- GEMM: C[co][n,h,w] = sum_k wq[co][k] * xt[...] ----------------
// R11 = R10's fine-phase interleave with the synchronization rebuilt.
//   R10 bug: p3 "early-read" of As[cur^1] was guarded only by the wave-LOCAL
//   vmcnt(0); other waves' DMA portions of the panel had no barrier before the
//   read -> cross-wave race -> absmax 255. Fix: no early-read. Window-end is
//   a FULL drain (lgkmcnt(0) + vmcnt(0) + s_barrier) -- every outstanding op
//   there is >=1 phase (~300cy) old, so the drains are nearly free, and the
//   As ring handoff is unambiguous under any compiler load ordering. fi0's
//   A-frags are read at window top instead (~120cy/window exposed, ~2us).
//   Mid-window: counted lgkmcnt(2/6) per phase (never 0), each phase
//   {issue next reads -> counted wait -> 4 MFMA} so LDS and matrix pipes
//   overlap instead of the R5..R9 monolithic convoy (m233 regime).
// Block 256x128 (all co), 4 waves, wave 128co x 64sp, 4x2 frags of
// mfma_i32_32x32x32_i8 (layouts validated R4/R6). A: DMA ring-2, issued at
// p0 for kt+1 (full-window latency cover). B: persistent swizzled Bp.
// LDS: Bp 33792 + As 2x16384 = 66560 -> 2 blocks/CU. Grid 896 = 8 XCD x 112.
__global__ __launch_bounds__(256, 2) void qconv_gemm(
    const char* __restrict__ xt, const char* __restrict__ wq3,
    const float* __restrict__ bias, const float* __restrict__ scale,
    const int* __restrict__ pmin, const int* __restrict__ pmax,
    float* __restrict__ out) {
  __shared__ __align__(16) char Bp[4 * 8448];   // 33792 B: 4 xt rows, swizzled chunks
  __shared__ __align__(16) char As[2][16384];   // ring-2: [mhalf2][chunk4][co128][16]

  int bid = blockIdx.x;        // 896 = 8 XCD x 112
  int xcd = bid & 7;
  int nt  = xcd * 112 + (bid >> 3);
  int n   = nt / 28;
  int ht  = nt - n * 28;
  int h0  = ht * 2;

  int t   = threadIdx.x;
  int wv  = t >> 6;
  int ln  = t & 63;
  int l31 = ln & 31;
  int hi  = ln >> 5;           // 16B half of each 32-k chunk
  int wm  = wv & 1, wn = wv >> 1;

  const char* xb = xt + (size_t)n * XT_N_STRIDE + (size_t)h0 * XT_H_STRIDE;

  // ---- stage Bp (once): slot s holds global chunk (row, w, cq^(w&7)) ----
  for (int it = 0; it < 9; ++it) {
    int s = t + it * 256;
    if (s < 2112) {                     // tail: only wave 0, full 64 lanes
      int row = s / 528;
      int rr  = s - row * 528;
      int w   = rr >> 3;
      int cq  = rr & 7;
      gload16(xb + row * XT_H_STRIDE + w * 128 + ((cq ^ (w & 7)) << 4),
              Bp + it * 4096 + wv * 1024);
    }
  }
  // ---- DMA A panel kt=0 -> As[0] (linear both sides) ----
#pragma unroll
  for (int ps = 0; ps < 4; ++ps)
    gload16(wq3 + ps * 4096 + t * 16, As[0] + ps * 4096 + wv * 1024);

  asm volatile("s_waitcnt vmcnt(0)" ::: "memory");   // Bp + As[0] landed (all waves: barrier)
  asm volatile("s_barrier" ::: "memory");

  // A-frag addr within a panel: wm*8192 + (kk*2+hi)*2048 + (fi*32+l31)*16
  const int aoff = wm * 8192 + hi * 2048 + l31 * 16;

  // ---- preload B for kt=0 (g=0: kh=0, kw=0, p=0) ----
  v4i af[2], ag[2], b[4], bn[4];
  {
    const char* bb = Bp + wn * XT_H_STRIDE + l31 * 128;
    int sm = l31 & 7;
    b[0] = *(const v4i*)(bb + (((0 + hi) ^ sm) << 4));
    b[1] = *(const v4i*)(bb + (((2 + hi) ^ sm) << 4));
    b[2] = *(const v4i*)(bb + 4096 + (((0 + hi) ^ sm) << 4));
    b[3] = *(const v4i*)(bb + 4096 + (((2 + hi) ^ sm) << 4));
  }

  v16i acc[4][2];
#pragma unroll
  for (int i = 0; i < 4; ++i)
#pragma unroll
    for (int j = 0; j < 2; ++j) {
      v16i z = {0};
      acc[i][j] = z;
    }

#pragma unroll
  for (int kt = 0; kt < 18; ++kt) {
    const int cur = kt & 1;
    const char* ap = As[cur];

    // ---- p0: DMA kt+1 (buffer freed at last window's full-drain barrier);
    //      read A fi=0 + fi=1; drain carried b + fi=0, leave fi=1 in flight ----
    if (kt < 17) {
      const char* src = wq3 + (size_t)(kt + 1) * 16384;
      char* dst = As[cur ^ 1];
#pragma unroll
      for (int ps = 0; ps < 4; ++ps)
        gload16(src + ps * 4096 + t * 16, dst + ps * 4096 + wv * 1024);
    }
    af[0] = *(const v4i*)(ap + aoff);
    af[1] = *(const v4i*)(ap + aoff + 4096);
    ag[0] = *(const v4i*)(ap + aoff + 1 * 512);
    ag[1] = *(const v4i*)(ap + aoff + 4096 + 1 * 512);
    asm volatile("s_waitcnt lgkmcnt(2)" ::: "memory");
    __builtin_amdgcn_sched_barrier(0);
    __builtin_amdgcn_s_setprio(1);
    acc[0][0] = __builtin_amdgcn_mfma_i32_32x32x32_i8(af[0], b[0], acc[0][0], 0, 0, 0);
    acc[0][0] = __builtin_amdgcn_mfma_i32_32x32x32_i8(af[1], b[1], acc[0][0], 0, 0, 0);
    acc[0][1] = __builtin_amdgcn_mfma_i32_32x32x32_i8(af[0], b[2], acc[0][1], 0, 0, 0);
    acc[0][1] = __builtin_amdgcn_mfma_i32_32x32x32_i8(af[1], b[3], acc[0][1], 0, 0, 0);
    __builtin_amdgcn_s_setprio(0);
    af[0] = ag[0]; af[1] = ag[1];

    // ---- p1: read A fi=2; drain fi=1 ----
    ag[0] = *(const v4i*)(ap + aoff + 2 * 512);
    ag[1] = *(const v4i*)(ap + aoff + 4096 + 2 * 512);
    asm volatile("s_waitcnt lgkmcnt(2)" ::: "memory");
    __builtin_amdgcn_sched_barrier(0);
    __builtin_amdgcn_s_setprio(1);
    acc[1][0] = __builtin_amdgcn_mfma_i32_32x32x32_i8(af[0], b[0], acc[1][0], 0, 0, 0);
    acc[1][0] = __builtin_amdgcn_mfma_i32_32x32x32_i8(af[1], b[1], acc[1][0], 0, 0, 0);
    acc[1][1] = __builtin_amdgcn_mfma_i32_32x32x32_i8(af[0], b[2], acc[1][1], 0, 0, 0);
    acc[1][1] = __builtin_amdgcn_mfma_i32_32x32x32_i8(af[1], b[3], acc[1][1], 0, 0, 0);
    __builtin_amdgcn_s_setprio(0);
    af[0] = ag[0]; af[1] = ag[1];

    // ---- p2: read A fi=3 + B(kt+1); drain fi=2, leave fi=3 + bn ----
    ag[0] = *(const v4i*)(ap + aoff + 3 * 512);
    ag[1] = *(const v4i*)(ap + aoff + 4096 + 3 * 512);
    if (kt < 17) {
      const int kn  = kt + 1;
      const int pn  = kn & 1;
      const int gn  = kn >> 1;
      const int khn = gn / 3;
      const int kwn = gn - 3 * khn;
      const char* bbn = Bp + (wn + khn) * XT_H_STRIDE + (l31 + kwn) * 128;
      int smn = (l31 + kwn) & 7;
      bn[0] = *(const v4i*)(bbn + ((((pn << 2) + 0 + hi) ^ smn) << 4));
      bn[1] = *(const v4i*)(bbn + ((((pn << 2) + 2 + hi) ^ smn) << 4));
      bn[2] = *(const v4i*)(bbn + 4096 + ((((pn << 2) + 0 + hi) ^ smn) << 4));
      bn[3] = *(const v4i*)(bbn + 4096 + ((((pn << 2) + 2 + hi) ^ smn) << 4));
      asm volatile("s_waitcnt lgkmcnt(6)" ::: "memory");
    } else {
      asm volatile("s_waitcnt lgkmcnt(2)" ::: "memory");
    }
    __builtin_amdgcn_sched_barrier(0);
    __builtin_amdgcn_s_setprio(1);
    acc[2][0] = __builtin_amdgcn_mfma_i32_32x32x32_i8(af[0], b[0], acc[2][0], 0, 0, 0);
    acc[2][0] = __builtin_amdgcn_mfma_i32_32x32x32_i8(af[1], b[1], acc[2][0], 0, 0, 0);
    acc[2][1] = __builtin_amdgcn_mfma_i32_32x32x32_i8(af[0], b[2], acc[2][1], 0, 0, 0);
    acc[2][1] = __builtin_amdgcn_mfma_i32_32x32x32_i8(af[1], b[3], acc[2][1], 0, 0, 0);
    __builtin_amdgcn_s_setprio(0);
    af[0] = ag[0]; af[1] = ag[1];

    // ---- p3: FULL drain (everything outstanding is >=1 phase old -> cheap);
    //      MFMA fi=3; window-end vmcnt(0)+barrier hands As[cur] to kt+1's DMA ----
    asm volatile("s_waitcnt lgkmcnt(0)" ::: "memory");
    __builtin_amdgcn_sched_barrier(0);
    __builtin_amdgcn_s_setprio(1);
    acc[3][0] = __builtin_amdgcn_mfma_i32_32x32x32_i8(af[0], b[0], acc[3][0], 0, 0, 0);
    acc[3][0] = __builtin_amdgcn_mfma_i32_32x32x32_i8(af[1], b[1], acc[3][0], 0, 0, 0);
    acc[3][1] = __builtin_amdgcn_mfma_i32_32x32x32_i8(af[0], b[2], acc[3][1], 0, 0, 0);
    acc[3][1] = __builtin_amdgcn_mfma_i32_32x32x32_i8(af[1], b[3], acc[3][1], 0, 0, 0);
    __builtin_amdgcn_s_setprio(0);
    if (kt < 17) {
#pragma unroll
      for (int u = 0; u < 4; ++u) b[u] = bn[u];   // renamed by full unroll
      // DMA(kt+1) landed everywhere after this wave-wise drain + barrier;
      // all As[cur] reads are drained (lgkmcnt(0) above) -> safe WAR handoff.
      asm volatile("s_waitcnt vmcnt(0)" ::: "memory");
      asm volatile("s_barrier" ::: "memory");
    }
  }

  // epilogue (32x32 C/D layout, validated R4):
  // co = wm*128 + fi*32 + (rg&3) + 8*(rg>>2) + 4*hi ; w = fj*32+l31 ; dh = wn
  float mn = (float)pmin[0];
  float mx = (float)pmax[0];
#pragma unroll
  for (int fi = 0; fi < 4; ++fi) {
#pragma unroll
    for (int rg = 0; rg < 16; ++rg) {
      int co = wm * 128 + fi * 32 + (rg & 3) + 8 * (rg >> 2) + 4 * hi;
      float bs = bias[co];
      float sc = scale[co];
      size_t obase = ((size_t)(n * 256 + co) * 56 + (h0 + wn)) * 56;
#pragma unroll
      for (int fj = 0; fj < 2; ++fj) {
        int w = fj * 32 + l31;
        if (w < 56) {
          float f = (float)acc[fi][fj][rg] + bs;
          f = rintf(f * sc);                 // half-to-even, matches np.round
          f = fminf(fmaxf(f, mn), mx);
          out[obase + w] = f;
        }
      }
    }
  }
}

extern "C" void kernel_launch(void* const* d_in, const int* in_sizes, int n_in,
                              void* d_out, int out_size, void* d_ws, size_t ws_size,
                              hipStream_t stream) {
  const float* x  = (const float*)d_in[0];
  const float* w  = (const float*)d_in[1];
  const float* b  = (const float*)d_in[2];
  const int*   Aq = (const int*)d_in[3];
  const int*   Nq = (const int*)d_in[4];
  const int*   mn = (const int*)d_in[5];
  const int*   mx = (const int*)d_in[6];
  float* out = (float*)d_out;

  char*  xt    = (char*)d_ws;                  // 15,679,488 B
  char*  wq3   = xt + XT_BYTES;                // 294,912 B (kt/mhalf/chunk layout)
  float* scale = (float*)(wq3 + WQ_BYTES);     // 1 KiB

  hipLaunchKernelGGL(xform_x, dim3(32 * 58), dim3(256), 0, stream, x, xt);
  hipLaunchKernelGGL(xform_w, dim3(1152), dim3(256), 0, stream, w, Aq, Nq, wq3, scale);
  hipLaunchKernelGGL(qconv_gemm, dim3(896), dim3(256), 0, stream,
                     xt, wq3, b, scale, mn, mx, out);
}

// Round 9
// 189.417 us; speedup vs baseline: 1.0500x; 1.0500x over previous
//
#include <hip/hip_runtime.h>
#include <stdint.h>

typedef int   v4i __attribute__((ext_vector_type(4)));
typedef float v4f __attribute__((ext_vector_type(4)));

// xt layout: [n][hp=58][wp=66][ci=128] int8, zero-padded (hp-1,wp-1 are src coords)
#define XT_H_STRIDE (66*128)          // 8448
#define XT_N_STRIDE (58*66*128)       // 489984
#define XT_BYTES    (32*58*66*128)    // 15,679,488
#define WQ_BYTES    (256*1152)        // 294,912

__device__ __forceinline__ void gload16(const void* g, void* l) {
  __builtin_amdgcn_global_load_lds(
      (const __attribute__((address_space(1))) void*)g,
      (__attribute__((address_space(3))) void*)l, 16, 0, 0);
}

// ---------------- x transform: fp32 NCHW -> int8 [n][hp][wp][ci] ----------------
// Coalesced both sides via LDS transpose. Unchanged (proven).
__global__ __launch_bounds__(256) void xform_x(const float* __restrict__ x,
                                               char* __restrict__ xt) {
  __shared__ int LB[56 * 33];          // [w][32 ci-dwords + 1 pad]
  int bid = blockIdx.x;                // 32*58
  int n  = bid / 58;
  int hp = bid - n * 58;
  int t  = threadIdx.x;
  int srch = hp - 1;
  bool rowok = (srch >= 0) && (srch < 56);
  char* dstrow = xt + (size_t)n * XT_N_STRIDE + (size_t)hp * XT_H_STRIDE;

  if (rowok) {
    const float* rb = x + ((size_t)(n * 128) * 56 + srch) * 56;   // + ci*3136 + w
#pragma unroll
    for (int u0 = 0; u0 < 2; ++u0) {
      int u  = t + u0 * 256;
      int wb = u & 15;
      int cb = u >> 4;
      int w0 = wb * 4, ci0 = cb * 4;
      if (w0 < 56) {
        int dw[4] = {0, 0, 0, 0};
#pragma unroll
        for (int i = 0; i < 4; ++i) {
          v4f f = *(const v4f*)(rb + (size_t)(ci0 + i) * 3136 + w0);
#pragma unroll
          for (int j = 0; j < 4; ++j)
            dw[j] |= (((int)f[j]) & 255) << (8 * i);
        }
#pragma unroll
        for (int j = 0; j < 4; ++j)
          LB[(w0 + j) * 33 + cb] = dw[j];
      }
    }
    __syncthreads();
    for (int c = t; c < 528; c += 256) {
      int wp  = c >> 3;
      int cio = c & 7;
      int srw = wp - 1;
      v4i v = {0, 0, 0, 0};
      if (srw >= 0 && srw < 56) {
#pragma unroll
        for (int k = 0; k < 4; ++k) v[k] = LB[srw * 33 + cio * 4 + k];
      }
      *(v4i*)(dstrow + c * 16) = v;
    }
  } else {
    v4i z = {0, 0, 0, 0};
    for (int c = t; c < 528; c += 256) *(v4i*)(dstrow + c * 16) = z;
  }
}

// ---------------- w transform: OIHW fp32 -> int8 wq3 + scale ----------------
// R9 layout (validated R9/R11): [kt18][mhalf2][chunk4][co128][16] int8.
// Per (kt, mhalf) the 8KB panel is DMA-linear and A-frag ds_reads are
// lane-contiguous (2-way bank aliasing = free).
__global__ __launch_bounds__(256) void xform_w(const float* __restrict__ wsrc,
                                               const int* __restrict__ Aq,
                                               const int* __restrict__ Nq,
                                               char* __restrict__ wq3,
                                               float* __restrict__ scale) {
  int idx = blockIdx.x * 256 + threadIdx.x;    // 294912
  int co = idx / 1152;
  int k  = idx - co * 1152;          // K index: g*128 + ci
  int g  = k >> 7;
  int ci = k & 127;
  int kh = g / 3;
  int kw = g - 3 * kh;
  float f = wsrc[(size_t)(co * 128 + ci) * 9 + kh * 3 + kw];
  int kt    = k >> 6;                // 0..17 (BK=64 window)
  int mhalf = co >> 7;
  int chunk = (k >> 4) & 3;          // 16B k-chunk within BK=64
  int row   = co & 127;
  int col   = k & 15;
  wq3[(((kt * 2 + mhalf) * 4 + chunk) * 128 + row) * 16 + col] = (signed char)(int)f;
  if (idx < 256) {
    scale[idx] = (float)Aq[idx] * exp2f(-(float)Nq[idx]);   // exact: A < 2^15
  }
}

// ---------------- GEMM: C[co][n,h,w] = sum_k wq[co][k] * xt[...] ----------------
// R12: OCCUPANCY, not scheduling. R5..R11 (six different schedules) all
// plateau at 60-67us with MfmaUtil~20%, VALU~15%, LDS~30%, occupancy 2
// blocks/CU: no pipe saturated -> latency-bound at 2 waves/SIMD. m97 proves
// the same naive 2-barrier loop reaches 36% of peak at 12 waves/CU. So:
// drop persistent Bp (xt is L2-resident; re-stage B per kt), shrink LDS to
// 2x(8K A + 8K B) = 32KB -> 4 blocks/CU; cap VGPR <=128 via
// __launch_bounds__(256,4) -> 16 waves/CU (2-3x prior TLP).
// Per kt: barrier; DMA next A+B (4 gload16/wave); vmcnt(4) [current buf's 4
// landed, new 4 in flight]; barrier; plain C++ frag reads (compiler emits
// fine-grained lgkmcnt - m97 evidence) + 16 MFMA. No setprio/sched games.
// A: wq3 panels, linear DMA, conflict-free reads (R9-validated).
// B: per-kt xt slab [sp128][64B], source pre-swizzled chunk^(sp&3)
//    (64B-coalesced source, 4-way read conflict = mild).
// 128x128 tile, 4 waves (2x2), 4x4 frags mfma_i32_16x16x64_i8 (R5 layouts).
// Grid 1792 (R5 mt/nt XCD swizzle).
__global__ __launch_bounds__(256, 4) void qconv_gemm(
    const char* __restrict__ xt, const char* __restrict__ wq3,
    const float* __restrict__ bias, const float* __restrict__ scale,
    const int* __restrict__ pmin, const int* __restrict__ pmax,
    float* __restrict__ out) {
  __shared__ __align__(16) char As[2][8192];   // [chunk4][co128][16]
  __shared__ __align__(16) char Bs[2][8192];   // [sp128][chunk^ (sp&3) 4][16]

  // XCD-aware swizzle: mt pair (shared xt rows) + contiguous nt range per XCD.
  int bid = blockIdx.x;        // 1792
  int xcd = bid & 7;
  int q   = bid >> 3;
  int mt  = q & 1;
  int nt  = xcd * 112 + (q >> 1);
  int n   = nt / 28;
  int ht  = nt - n * 28;
  int h0  = ht * 2;
  int m0  = mt * 128;

  int t  = threadIdx.x;
  int wv = t >> 6;
  int ln = t & 63;
  int quad = ln >> 4;
  int l16  = ln & 15;
  int wm = wv & 1, wn = wv >> 1;

  const char* xb = xt + (size_t)n * XT_N_STRIDE + (size_t)h0 * XT_H_STRIDE;

  // B DMA per-lane source voffsets (kt-invariant): slot s = wv*64 + u*256 + ln
  // -> sp = s>>2 (dh = sp>>6, w = sp&63), ck = s&3, swizzled chunk = ck^(sp&3).
  int boffv[2];
#pragma unroll
  for (int u = 0; u < 2; ++u) {
    int s  = wv * 64 + u * 256 + ln;
    int sp = s >> 2;
    int ck = s & 3;
    boffv[u] = (sp >> 6) * XT_H_STRIDE + (sp & 63) * 128 + ((ck ^ (sp & 3)) << 4);
  }
  // frag-read offsets
  const int aoff = quad * 2048 + (wm * 64 + l16) * 16;                 // + i*256
  const int boff = (wn * 64 + l16) * 64 + ((quad ^ (l16 & 3)) << 4);   // + j*1024

  // ---- prologue: DMA kt=0 into buf 0 (A: wq3 panel; B: xt slab, koff=0) ----
  {
    const char* a0 = wq3 + (size_t)mt * 8192;
    gload16(a0 + t * 16,        As[0] + wv * 1024);
    gload16(a0 + 4096 + t * 16, As[0] + 4096 + wv * 1024);
    gload16(xb + boffv[0],      Bs[0] + wv * 1024);
    gload16(xb + boffv[1],      Bs[0] + 4096 + wv * 1024);
  }
  asm volatile("s_waitcnt vmcnt(0)" ::: "memory");
  asm volatile("s_barrier" ::: "memory");

  v4i acc[4][4];
#pragma unroll
  for (int i = 0; i < 4; ++i)
#pragma unroll
    for (int j = 0; j < 4; ++j) {
      v4i z = {0, 0, 0, 0};
      acc[i][j] = z;
    }

#pragma unroll
  for (int kt = 0; kt < 18; ++kt) {
    const int buf = kt & 1;

    // all waves finished reading buf^1 (in kt-1) -> safe to DMA-overwrite it
    asm volatile("s_barrier" ::: "memory");
    if (kt < 17) {
      const int kn  = kt + 1;
      const int gn  = kn >> 1;
      const int pn  = kn & 1;
      const int khn = gn / 3;
      const int kwn = gn - 3 * khn;
      const int koff = khn * XT_H_STRIDE + kwn * 128 + pn * 64;  // uniform
      const char* an = wq3 + (size_t)(kn * 2 + mt) * 8192;
      const char* bn = xb + koff;
      gload16(an + t * 16,        As[buf ^ 1] + wv * 1024);
      gload16(an + 4096 + t * 16, As[buf ^ 1] + 4096 + wv * 1024);
      gload16(bn + boffv[0],      Bs[buf ^ 1] + wv * 1024);
      gload16(bn + boffv[1],      Bs[buf ^ 1] + 4096 + wv * 1024);
      asm volatile("s_waitcnt vmcnt(4)" ::: "memory");  // current buf landed
    } else {
      asm volatile("s_waitcnt vmcnt(0)" ::: "memory");
    }
    asm volatile("s_barrier" ::: "memory");             // cross-wave: buf ready

    // frag reads: plain C++ -> compiler emits fine-grained lgkmcnt (m97).
    v4i a[4], b[4];
#pragma unroll
    for (int i = 0; i < 4; ++i)
      a[i] = *(const v4i*)(As[buf] + aoff + i * 256);
#pragma unroll
    for (int j = 0; j < 4; ++j)
      b[j] = *(const v4i*)(Bs[buf] + boff + j * 1024);
#pragma unroll
    for (int i = 0; i < 4; ++i)
#pragma unroll
      for (int j = 0; j < 4; ++j)
        acc[i][j] = __builtin_amdgcn_mfma_i32_16x16x64_i8(a[i], b[j], acc[i][j], 0, 0, 0);
  }

  // epilogue (R5-validated): co = m0 + wm*64 + i*16 + quad*4 + r ;
  // spatial sl = wn*64 + j*16 + l16 -> w = sl&63, dh = sl>>6
  float mn = (float)pmin[0];
  float mx = (float)pmax[0];
#pragma unroll
  for (int i = 0; i < 4; ++i) {
    int co_b = m0 + wm * 64 + i * 16 + quad * 4;
#pragma unroll
    for (int r = 0; r < 4; ++r) {
      int co = co_b + r;
      float bs = bias[co];
      float sc = scale[co];
#pragma unroll
      for (int j = 0; j < 4; ++j) {
        int sl = wn * 64 + j * 16 + l16;
        int w  = sl & 63;
        int dh = sl >> 6;
        if (w < 56) {
          float f = (float)acc[i][j][r] + bs;
          f = rintf(f * sc);                 // half-to-even, matches np.round
          f = fminf(fmaxf(f, mn), mx);
          out[(((size_t)n * 256 + co) * 56 + (h0 + dh)) * 56 + w] = f;
        }
      }
    }
  }
}

extern "C" void kernel_launch(void* const* d_in, const int* in_sizes, int n_in,
                              void* d_out, int out_size, void* d_ws, size_t ws_size,
                              hipStream_t stream) {
  const float* x  = (const float*)d_in[0];
  const float* w  = (const float*)d_in[1];
  const float* b  = (const float*)d_in[2];
  const int*   Aq = (const int*)d_in[3];
  const int*   Nq = (const int*)d_in[4];
  const int*   mn = (const int*)d_in[5];
  const int*   mx = (const int*)d_in[6];
  float* out = (float*)d_out;

  char*  xt    = (char*)d_ws;                  // 15,679,488 B
  char*  wq3   = xt + XT_BYTES;                // 294,912 B (kt/mhalf/chunk layout)
  float* scale = (float*)(wq3 + WQ_BYTES);     // 1 KiB

  hipLaunchKernelGGL(xform_x, dim3(32 * 58), dim3(256), 0, stream, x, xt);
  hipLaunchKernelGGL(xform_w, dim3(1152), dim3(256), 0, stream, w, Aq, Nq, wq3, scale);
  hipLaunchKernelGGL(qconv_gemm, dim3(1792), dim3(256), 0, stream,
                     xt, wq3, b, scale, mn, mx, out);
}